// Round 6
// baseline (58.863 us; speedup 1.0000x reference)
//
#include <hip/hip_runtime.h>

// GetScalars: per-atom SO(3)-invariant Gram features.
// out[b][a][:] = concat( part0 scalars (32), gram_l for l=0..3 (4*1024) )
// gram_l[c][d] = sum_m part_l[..m..][c] * part_l[..m..][d]
//
// Memory-bound, write-dominated: 33.5 MB read + 270.5 MB write.
// Fill kernels on this buffer: 6.6-6.9 TB/s => floor ~50-53 us mixed.
//
// R6: 8 atoms / 256-thread block (2048 blocks).
//  - staging: 1024 float4 = exactly 4 per thread, ONE barrier per 8 atoms
//  - per-thread (c = t>>3, d = (t&7)*4); templated per-l gram keeps VGPR low
//  - nontemporal stores via native ext_vector float4 (HIP float4 class is
//    rejected by __builtin_nontemporal_store).

constexpr int C = 32;
constexpr int OUT_PER_ATOM = C + 4 * C * C;   // 4128 floats
constexpr int APB = 8;                        // atoms per block

typedef float f32x4 __attribute__((ext_vector_type(4)));

// gram float4 for rows [R0, R0+NM) at (c, d..d+3)
template <int R0, int NM>
__device__ __forceinline__ f32x4 gram4(const float* __restrict__ L, int c, int d) {
    f32x4 acc = {0.f, 0.f, 0.f, 0.f};
    #pragma unroll
    for (int m = 0; m < NM; ++m) {
        const float* row = L + (R0 + m) * C;
        const float pc = row[c];
        const f32x4 pd = *reinterpret_cast<const f32x4*>(row + d);
        acc += pc * pd;
    }
    return acc;
}

__global__ __launch_bounds__(256) void getscalars_kernel(
    const float* __restrict__ p0, const float* __restrict__ p1,
    const float* __restrict__ p2, const float* __restrict__ p3,
    float* __restrict__ out)
{
    // per atom: rows 0..15 = m-rows ([0]=l0, [1..3]=l1, [4..8]=l2, [9..15]=l3)
    __shared__ float lds[APB * 16 * C];   // 16 KB

    const int t = threadIdx.x;
    const int atom0 = blockIdx.x * APB;

    // Stage 8 atoms: 1024 float4, 4 per thread, coalesced per input array.
    #pragma unroll
    for (int s = 0; s < 4; ++s) {
        const int j = t + s * 256;        // 0..1023 quad in block
        const int a = j >> 7;             // atom within block
        const int k = j & 127;            // quad within atom (8/24/40/56 split)
        const int atom = atom0 + a;
        const f32x4* src;
        int idx;
        if (k < 8)       { src = (const f32x4*)(p0 + (size_t)atom * 32);  idx = k; }
        else if (k < 32) { src = (const f32x4*)(p1 + (size_t)atom * 96);  idx = k - 8; }
        else if (k < 72) { src = (const f32x4*)(p2 + (size_t)atom * 160); idx = k - 32; }
        else             { src = (const f32x4*)(p3 + (size_t)atom * 224); idx = k - 72; }
        reinterpret_cast<f32x4*>(lds)[j] = src[idx];
    }
    __syncthreads();

    const int c = t >> 3;         // 0..31
    const int d = (t & 7) * 4;    // 0,4,...,28

    for (int a = 0; a < APB; ++a) {
        const float* L = lds + a * 16 * C;
        float* outp = out + (size_t)(atom0 + a) * OUT_PER_ATOM;

        // scalars_part0: first 32 floats = row 0
        if (t < 8) {
            __builtin_nontemporal_store(reinterpret_cast<const f32x4*>(L)[t],
                                        reinterpret_cast<f32x4*>(outp) + t);
        }

        __builtin_nontemporal_store(gram4<0, 1>(L, c, d),
            reinterpret_cast<f32x4*>(outp + C + 0 * 1024 + 4 * t));
        __builtin_nontemporal_store(gram4<1, 3>(L, c, d),
            reinterpret_cast<f32x4*>(outp + C + 1 * 1024 + 4 * t));
        __builtin_nontemporal_store(gram4<4, 5>(L, c, d),
            reinterpret_cast<f32x4*>(outp + C + 2 * 1024 + 4 * t));
        __builtin_nontemporal_store(gram4<9, 7>(L, c, d),
            reinterpret_cast<f32x4*>(outp + C + 3 * 1024 + 4 * t));
    }
}

extern "C" void kernel_launch(void* const* d_in, const int* in_sizes, int n_in,
                              void* d_out, int out_size, void* d_ws, size_t ws_size,
                              hipStream_t stream) {
    const float* p0 = (const float*)d_in[0];
    const float* p1 = (const float*)d_in[1];
    const float* p2 = (const float*)d_in[2];
    const float* p3 = (const float*)d_in[3];
    float* out = (float*)d_out;

    const int natoms = in_sizes[0] / C;   // B * NUM_ATOMS = 16384
    getscalars_kernel<<<natoms / APB, 256, 0, stream>>>(p0, p1, p2, p3, out);
}

// Round 7
// 55.324 us; speedup vs baseline: 1.0640x; 1.0640x over previous
//
#include <hip/hip_runtime.h>

// GetScalars: per-atom SO(3)-invariant Gram features.
// out[b][a][:] = concat( part0 scalars (32), gram_l for l=0..3 (4*1024) )
// gram_l[c][d] = sum_m part_l[..m..][c] * part_l[..m..][d]
//
// Memory-bound, write-dominated: 33.5 MB read + 270.5 MB write.
// D2D copy achieves 6.3 TB/s combined => floor ~48 us.
//
// R7 structure: 4 atoms / 256-thread block (4096 blocks), wave-per-l:
//  wave w computes gram l=w entirely. Each lane owns (c0 + {0,8,16,24}, dq):
//  one pd b128 LDS read serves 4 accumulators -> LDS traffic halved vs
//  thread-per-(c,dq); acc+pd = ~20 VGPR live -> high occupancy; each wave's
//  stores walk one contiguous 4KB region (one write stream per wave).

constexpr int C = 32;
constexpr int OUT_PER_ATOM = C + 4 * C * C;   // 4128 floats
constexpr int APB = 4;                        // atoms per block

typedef float f32x4 __attribute__((ext_vector_type(4)));

// Wave-level gram for one l: lane computes (c0+8k, dq..dq+3), k=0..3.
template <int LV>
__device__ __forceinline__ void gram_wave(const float* __restrict__ Lp,
                                          int lane, float* __restrict__ outp) {
    constexpr int R0 = LV * LV;
    constexpr int NM = 2 * LV + 1;
    const int dq = (lane & 7) * 4;    // d offset (floats)
    const int c0 = lane >> 3;         // base c (0..7)

    f32x4 a0 = {0.f, 0.f, 0.f, 0.f}, a1 = a0, a2 = a0, a3 = a0;
    #pragma unroll
    for (int m = 0; m < NM; ++m) {
        const float* row = Lp + (R0 + m) * C;
        const f32x4 pd = *reinterpret_cast<const f32x4*>(row + dq);
        a0 += row[c0     ] * pd;
        a1 += row[c0 +  8] * pd;
        a2 += row[c0 + 16] * pd;
        a3 += row[c0 + 24] * pd;
    }
    // gram entry [c][d] at gbase + c*32 + d; per-store addr = 256*k + 4*lane
    // -> each store is a contiguous 1KB wave burst, 4 stores walk 4KB.
    float* gbase = outp + C + LV * 1024;
    *reinterpret_cast<f32x4*>(gbase + (c0     ) * C + dq) = a0;
    *reinterpret_cast<f32x4*>(gbase + (c0 +  8) * C + dq) = a1;
    *reinterpret_cast<f32x4*>(gbase + (c0 + 16) * C + dq) = a2;
    *reinterpret_cast<f32x4*>(gbase + (c0 + 24) * C + dq) = a3;
}

__global__ __launch_bounds__(256, 6) void getscalars_kernel(
    const float* __restrict__ p0, const float* __restrict__ p1,
    const float* __restrict__ p2, const float* __restrict__ p3,
    float* __restrict__ out)
{
    // per atom: rows 0..15 = m-rows ([0]=l0, [1..3]=l1, [4..8]=l2, [9..15]=l3)
    __shared__ float lds[APB * 16 * C];   // 8 KB

    const int t = threadIdx.x;
    const int atom0 = blockIdx.x * APB;

    // Stage 4 atoms: 512 float4, 2 per thread, coalesced per input array.
    #pragma unroll
    for (int s = 0; s < 2; ++s) {
        const int j = t + s * 256;        // 0..511 quad in block
        const int a = j >> 7;             // atom within block
        const int k = j & 127;            // quad within atom (8/24/40/56 split)
        const int atom = atom0 + a;
        const f32x4* src;
        int idx;
        if (k < 8)       { src = (const f32x4*)(p0 + (size_t)atom * 32);  idx = k; }
        else if (k < 32) { src = (const f32x4*)(p1 + (size_t)atom * 96);  idx = k - 8; }
        else if (k < 72) { src = (const f32x4*)(p2 + (size_t)atom * 160); idx = k - 32; }
        else             { src = (const f32x4*)(p3 + (size_t)atom * 224); idx = k - 72; }
        reinterpret_cast<f32x4*>(lds)[j] = src[idx];
    }
    __syncthreads();

    const int w = t >> 6;     // wave id = which l this wave owns
    const int lane = t & 63;

    for (int a = 0; a < APB; ++a) {
        const float* Lp = lds + a * 16 * C;
        float* outp = out + (size_t)(atom0 + a) * OUT_PER_ATOM;

        if (w == 0) {
            // scalars_part0: first 32 floats = row 0
            if (lane < 8) {
                reinterpret_cast<f32x4*>(outp)[lane] =
                    reinterpret_cast<const f32x4*>(Lp)[lane];
            }
            gram_wave<0>(Lp, lane, outp);
        } else if (w == 1) {
            gram_wave<1>(Lp, lane, outp);
        } else if (w == 2) {
            gram_wave<2>(Lp, lane, outp);
        } else {
            gram_wave<3>(Lp, lane, outp);
        }
    }
}

extern "C" void kernel_launch(void* const* d_in, const int* in_sizes, int n_in,
                              void* d_out, int out_size, void* d_ws, size_t ws_size,
                              hipStream_t stream) {
    const float* p0 = (const float*)d_in[0];
    const float* p1 = (const float*)d_in[1];
    const float* p2 = (const float*)d_in[2];
    const float* p3 = (const float*)d_in[3];
    float* out = (float*)d_out;

    const int natoms = in_sizes[0] / C;   // B * NUM_ATOMS = 16384
    getscalars_kernel<<<natoms / APB, 256, 0, stream>>>(p0, p1, p2, p3, out);
}